// Round 5
// baseline (475.359 us; speedup 1.0000x reference)
//
#include <hip/hip_runtime.h>
#include <hip/hip_bf16.h>
#include <math.h>

#define B_ 64
#define L_ 512
#define D_ 768
#define J_ 31
#define S_ 32
#define H_ 100
#define G3 300
#define NC_ 10
#define EMB_ 50

__device__ __forceinline__ float sigmoidf_(float x) { return 1.0f / (1.0f + __expf(-x)); }
__device__ __forceinline__ float tanhf_(float x) {
    float e = __expf(2.0f * x);          // +inf for large x -> 1; 0 for very neg -> -1
    return 1.0f - 2.0f / (e + 1.0f);
}
__device__ __forceinline__ float dot4_(float4 a, float4 b) {
    return a.x * b.x + a.y * b.y + a.z * b.z + a.w * b.w;
}

// ---------------------------------------------------------------------------
// K1: per-clause softmax-weighted pooling.  One block per (s, b).
// doc layout: [S][B][D]  (scan order)
// ---------------------------------------------------------------------------
#define TCAP 18
__global__ __launch_bounds__(256) void pool_kernel(
    const float* __restrict__ hs, const int* __restrict__ cb,
    const float* __restrict__ fc5w, const float* __restrict__ fc5b,
    float* __restrict__ doc)
{
    __shared__ __align__(16) float tile[TCAP * D_];
    __shared__ float sc_s[L_];
    __shared__ float red[8];

    int s = blockIdx.x, b = blockIdx.y;
    int start = (s == 0) ? 0 : cb[b * J_ + s - 1];
    int end   = (s == J_) ? L_ : cb[b * J_ + s];
    int nt = end - start;
    int tid = threadIdx.x;

    if (nt <= 0) {
        for (int d = tid; d < D_; d += 256) doc[((size_t)s * B_ + b) * D_ + d] = 0.f;
        return;
    }
    bool staged = (nt <= TCAP);
    const float* base = hs + ((size_t)b * L_ + start) * D_;

    if (staged) {
        const float4* b4 = (const float4*)base;
        float4* t4 = (float4*)tile;
        int n4 = nt * (D_ / 4);
        for (int i = tid; i < n4; i += 256) t4[i] = b4[i];
    }
    int lane = tid & 63, wv = tid >> 6;
    float fw[12];
#pragma unroll
    for (int i = 0; i < 12; ++i) fw[i] = fc5w[i * 64 + lane];
    __syncthreads();

    for (int t = wv; t < nt; t += 4) {
        const float* row = staged ? &tile[t * D_] : (base + (size_t)t * D_);
        float p = 0.f;
#pragma unroll
        for (int i = 0; i < 12; ++i) p += row[i * 64 + lane] * fw[i];
        for (int off = 32; off; off >>= 1) p += __shfl_xor(p, off);
        if (lane == 0) sc_s[t] = p + fc5b[0];
    }
    __syncthreads();

    float lm = -INFINITY;
    for (int i = tid; i < nt; i += 256) lm = fmaxf(lm, sc_s[i]);
    for (int off = 32; off; off >>= 1) lm = fmaxf(lm, __shfl_xor(lm, off));
    if (lane == 0) red[wv] = lm;
    __syncthreads();
    float mx = fmaxf(fmaxf(red[0], red[1]), fmaxf(red[2], red[3]));
    float ls = 0.f;
    for (int i = tid; i < nt; i += 256) {
        float e = expf(sc_s[i] - mx);
        sc_s[i] = e;
        ls += e;
    }
    for (int off = 32; off; off >>= 1) ls += __shfl_xor(ls, off);
    if (lane == 0) red[4 + wv] = ls;
    __syncthreads();
    float inv = 1.f / (red[4] + red[5] + red[6] + red[7]);

    float acc0 = 0.f, acc1 = 0.f, acc2 = 0.f;
    for (int t = 0; t < nt; ++t) {
        float w = sc_s[t] * inv;
        const float* row = staged ? &tile[t * D_] : (base + (size_t)t * D_);
        acc0 += w * row[tid];
        acc1 += w * row[256 + tid];
        acc2 += w * row[512 + tid];
    }
    float* o = doc + ((size_t)s * B_ + b) * D_;
    o[tid] = acc0; o[256 + tid] = acc1; o[512 + tid] = acc2;
}

// ---------------------------------------------------------------------------
// K2: gi = doc @ [Wf;Wb].T + [bf;bb]   M=2048, N=600, K=768  (64x64 tiles)
// ---------------------------------------------------------------------------
__global__ __launch_bounds__(256) void gemm_enc(
    const float* __restrict__ A,
    const float* __restrict__ Wf, const float* __restrict__ Wb,
    const float* __restrict__ bf_, const float* __restrict__ bb_,
    float* __restrict__ C)
{
    __shared__ __align__(16) float As[16][68];
    __shared__ __align__(16) float Ws[16][68];
    int n0 = blockIdx.x * 64, m0 = blockIdx.y * 64;
    int tid = threadIdx.x;
    int tx = tid & 15, ty = tid >> 4;
    int lr = tid >> 2, lk4 = tid & 3;
    float acc[4][4] = {};

    for (int kk = 0; kk < D_; kk += 16) {
        float4 av = *(const float4*)(A + ((size_t)(m0 + lr)) * D_ + kk + lk4 * 4);
        As[lk4 * 4 + 0][lr] = av.x; As[lk4 * 4 + 1][lr] = av.y;
        As[lk4 * 4 + 2][lr] = av.z; As[lk4 * 4 + 3][lr] = av.w;
        int n = n0 + lr;
        float4 wvv = make_float4(0.f, 0.f, 0.f, 0.f);
        if (n < G3)      wvv = *(const float4*)(Wf + (size_t)n * D_ + kk + lk4 * 4);
        else if (n < 600) wvv = *(const float4*)(Wb + (size_t)(n - G3) * D_ + kk + lk4 * 4);
        Ws[lk4 * 4 + 0][lr] = wvv.x; Ws[lk4 * 4 + 1][lr] = wvv.y;
        Ws[lk4 * 4 + 2][lr] = wvv.z; Ws[lk4 * 4 + 3][lr] = wvv.w;
        __syncthreads();
#pragma unroll
        for (int k = 0; k < 16; ++k) {
            float4 a4 = *(const float4*)&As[k][ty * 4];
            float4 w4 = *(const float4*)&Ws[k][tx * 4];
            float ai[4] = {a4.x, a4.y, a4.z, a4.w};
            float wj[4] = {w4.x, w4.y, w4.z, w4.w};
#pragma unroll
            for (int i = 0; i < 4; ++i)
#pragma unroll
                for (int j = 0; j < 4; ++j) acc[i][j] += ai[i] * wj[j];
        }
        __syncthreads();
    }
#pragma unroll
    for (int j = 0; j < 4; ++j) {
        int n = n0 + tx * 4 + j;
        if (n >= 600) continue;
        float bias = (n < G3) ? bf_[n] : bb_[n - G3];
#pragma unroll
        for (int i = 0; i < 4; ++i) {
            int m = m0 + ty * 4 + i;
            C[(size_t)m * 600 + n] = acc[i][j] + bias;
        }
    }
}

// ---------------------------------------------------------------------------
// K3: encoder scans — SINGLE WAVE per (b,dir): barrier-free orchestration.
// lane l owns Whh rows {l, 64+l, 128+l, 192+l, 256+l(<300)} via LDS wt.
// ---------------------------------------------------------------------------
#define WT_N (25 * G3 * 4)   // 30000 floats = 120000 B
__global__ __launch_bounds__(64) void enc_scan(
    const float* __restrict__ gi,
    const float* __restrict__ whh_f, const float* __restrict__ whh_b,
    const float* __restrict__ bhh_f, const float* __restrict__ bhh_b,
    float* __restrict__ out1, float* __restrict__ hT)
{
    __shared__ __align__(16) float wt[WT_N];
    __shared__ __align__(16) float h_s[H_];
    __shared__ float gh_s[G3];

    int bid = blockIdx.x;
    int b = bid & 63;
    bool bwd = (bid >= 64);
    const float* whh = bwd ? whh_b : whh_f;
    const float* bhh = bwd ? bhh_b : bhh_f;
    int l = threadIdx.x;

    for (int i4 = l; i4 < 7500; i4 += 64) {
        int j = i4 / 25, k4 = i4 - j * 25;
        float4 v = *(const float4*)(whh + (size_t)j * H_ + k4 * 4);
        *(float4*)&wt[(k4 * G3 + j) * 4] = v;
    }
    float bh0 = bhh[l], bh1 = bhh[64 + l], bh2 = bhh[128 + l], bh3 = bhh[192 + l];
    float bh4 = (l < 44) ? bhh[256 + l] : 0.f;
    float hc0 = 0.f, hc1 = 0.f;
    h_s[l] = 0.f;
    if (l < 36) h_s[64 + l] = 0.f;
    __syncthreads();

    const int goff = bwd ? G3 : 0;
    const int ooff = bwd ? H_ : 0;
    const int row4 = 256 + ((l < 44) ? l : 0);   // clamp to stay in-bounds

    for (int step = 0; step < S_; ++step) {
        int t = bwd ? (S_ - 1 - step) : step;
        const float* g = gi + ((size_t)t * B_ + b) * 600 + goff;
        float ga0 = g[l], ga1 = g[100 + l], ga2 = g[200 + l];
        float gb0 = 0.f, gb1 = 0.f, gb2 = 0.f;
        if (l < 36) { gb0 = g[64 + l]; gb1 = g[164 + l]; gb2 = g[264 + l]; }

        float a0 = bh0, a1 = bh1, a2 = bh2, a3 = bh3, a4 = bh4;
#pragma unroll
        for (int k4 = 0; k4 < 25; ++k4) {
            float4 h4 = *(const float4*)&h_s[k4 * 4];
            a0 += dot4_(*(const float4*)&wt[(k4 * G3 + l) * 4], h4);
            a1 += dot4_(*(const float4*)&wt[(k4 * G3 + 64 + l) * 4], h4);
            a2 += dot4_(*(const float4*)&wt[(k4 * G3 + 128 + l) * 4], h4);
            a3 += dot4_(*(const float4*)&wt[(k4 * G3 + 192 + l) * 4], h4);
            a4 += dot4_(*(const float4*)&wt[(k4 * G3 + row4) * 4], h4);
        }
        gh_s[l] = a0; gh_s[64 + l] = a1; gh_s[128 + l] = a2; gh_s[192 + l] = a3;
        if (l < 44) gh_s[256 + l] = a4;
        __syncthreads();   // 1 wave: ~free, acts as LDS fence

        {
            float r = sigmoidf_(ga0 + gh_s[l]);
            float z = sigmoidf_(ga1 + gh_s[100 + l]);
            float n = tanhf_(ga2 + r * gh_s[200 + l]);
            float hn = (1.f - z) * n + z * hc0;
            hc0 = hn; h_s[l] = hn;
            out1[((size_t)t * B_ + b) * 200 + ooff + l] = hn;
        }
        if (l < 36) {
            float r = sigmoidf_(gb0 + gh_s[64 + l]);
            float z = sigmoidf_(gb1 + gh_s[164 + l]);
            float n = tanhf_(gb2 + r * gh_s[264 + l]);
            float hn = (1.f - z) * n + z * hc1;
            hc1 = hn; h_s[64 + l] = hn;
            out1[((size_t)t * B_ + b) * 200 + ooff + 64 + l] = hn;
        }
        __syncthreads();
    }
    if (!bwd) {
        hT[b * H_ + l] = hc0;
        if (l < 36) hT[b * H_ + 64 + l] = hc1;
    }
}

// ---------------------------------------------------------------------------
// K4a: per row n of dec_wih: W2[n] = dwih[n][50:150] @ l1w ; b2[n]; and the
// label table tcg[c][n] = bih[n] + emb[c] . dwih[n][0:50]
// ---------------------------------------------------------------------------
__global__ __launch_bounds__(256) void w2_precompute(
    const float* __restrict__ dwih, const float* __restrict__ l1w,
    const float* __restrict__ l1b, const float* __restrict__ emb,
    const float* __restrict__ bih,
    float* __restrict__ W2, float* __restrict__ b2, float* __restrict__ tcg)
{
    __shared__ float dw_s[H_];
    int n = blockIdx.x;
    int k = threadIdx.x;
    if (k < H_) dw_s[k] = dwih[(size_t)n * 150 + 50 + k];
    __syncthreads();
    if (k < 200) {
        float acc = 0.f;
        for (int i = 0; i < H_; ++i) acc += dw_s[i] * l1w[(size_t)i * 200 + k];
        W2[(size_t)n * 200 + k] = acc;
    } else if (k == 200) {
        float acc = 0.f;
        for (int i = 0; i < H_; ++i) acc += dw_s[i] * l1b[i];
        b2[n] = acc;
    } else if (k < 211) {
        int c = k - 201;
        float acc = bih[n];
        const float* er = emb + c * EMB_;
        const float* wr = dwih + (size_t)n * 150;
        for (int e = 0; e < EMB_; ++e) acc += er[e] * wr[e];
        tcg[c * G3 + n] = acc;
    }
}

// ---------------------------------------------------------------------------
// K4b: generic small NT GEMM: C[m][n] = sum_k A[m][k]*W[n][k] (+bias[n])
// ---------------------------------------------------------------------------
__global__ void small_gemm(
    const float* __restrict__ A, int lda, int K,
    const float* __restrict__ W, int wstride, int woff,
    const float* __restrict__ bias,
    float* __restrict__ C, int N, int ldc,
    int BM, int nChunk)
{
    extern __shared__ float sm[];
    int Kp = K + 1;
    float* Wl = sm;
    float* Al = sm + (size_t)nChunk * Kp;
    int nBase = blockIdx.x * nChunk;
    int nCnt = min(nChunk, N - nBase);
    int m0 = blockIdx.y * BM;

    for (int i = threadIdx.x; i < nCnt * K; i += blockDim.x) {
        int n = i / K, k = i - n * K;
        Wl[n * Kp + k] = W[(size_t)(nBase + n) * wstride + woff + k];
    }
    for (int i = threadIdx.x; i < BM * K; i += blockDim.x) {
        int mi = i / K, k = i - mi * K;
        Al[mi * Kp + k] = A[(size_t)(m0 + mi) * lda + k];
    }
    __syncthreads();

    for (int o = threadIdx.x; o < BM * nCnt; o += blockDim.x) {
        int mi = o / nCnt, n = o - mi * nCnt;
        const float* wr = &Wl[n * Kp];
        const float* ar = &Al[mi * Kp];
        float a0 = 0.f, a1 = 0.f, a2 = 0.f, a3 = 0.f;
        int k = 0;
        for (; k + 4 <= K; k += 4) {
            a0 += ar[k] * wr[k];
            a1 += ar[k + 1] * wr[k + 1];
            a2 += ar[k + 2] * wr[k + 2];
            a3 += ar[k + 3] * wr[k + 3];
        }
        for (; k < K; ++k) a0 += ar[k] * wr[k];
        float v = (a0 + a1) + (a2 + a3);
        if (bias) v += bias[nBase + n];
        C[(size_t)(m0 + mi) * ldc + nBase + n] = v;
    }
}

// ---------------------------------------------------------------------------
// K5: decoder greedy scan — SINGLE WAVE per batch element, barrier-free.
// ---------------------------------------------------------------------------
__global__ __launch_bounds__(64) void dec_scan(
    const float* __restrict__ gi_lin,
    const float* __restrict__ whh, const float* __restrict__ bhh,
    const float* __restrict__ tcg,
    const float* __restrict__ h2lw, const float* __restrict__ h2lb,
    const float* __restrict__ hT, float* __restrict__ out)
{
    __shared__ __align__(16) float wt[WT_N];     // 120000 B
    __shared__ float tc_s[NC_ * G3];             // 12000 B
    __shared__ float hl_s[NC_ * H_];             // 4000 B
    __shared__ __align__(16) float h_s[H_];
    __shared__ float gh_s[G3];
    __shared__ float lg_s[NC_];

    int b = blockIdx.x;
    int l = threadIdx.x;

    for (int i4 = l; i4 < 7500; i4 += 64) {
        int j = i4 / 25, k4 = i4 - j * 25;
        float4 v = *(const float4*)(whh + (size_t)j * H_ + k4 * 4);
        *(float4*)&wt[(k4 * G3 + j) * 4] = v;
    }
    for (int idx = l; idx < NC_ * G3; idx += 64) tc_s[idx] = tcg[idx];
    for (int idx = l; idx < NC_ * H_; idx += 64) hl_s[idx] = h2lw[idx];

    float bh0 = bhh[l], bh1 = bhh[64 + l], bh2 = bhh[128 + l], bh3 = bhh[192 + l];
    float bh4 = (l < 44) ? bhh[256 + l] : 0.f;
    float hc0 = hT[b * H_ + l];
    float hc1 = (l < 36) ? hT[b * H_ + 64 + l] : 0.f;
    h_s[l] = hc0;
    if (l < 36) h_s[64 + l] = hc1;
    float hlb_r = (l < 40 && (l & 3) == 0) ? h2lb[l >> 2] : 0.f;
    int prev = 0;
    __syncthreads();

    const int row4 = 256 + ((l < 44) ? l : 0);

    for (int t = 0; t < S_; ++t) {
        const float* g = gi_lin + ((size_t)t * B_ + b) * G3;
        float ga0 = g[l], ga1 = g[100 + l], ga2 = g[200 + l];
        float gb0 = 0.f, gb1 = 0.f, gb2 = 0.f;
        if (l < 36) { gb0 = g[64 + l]; gb1 = g[164 + l]; gb2 = g[264 + l]; }

        float a0 = bh0, a1 = bh1, a2 = bh2, a3 = bh3, a4 = bh4;
#pragma unroll
        for (int k4 = 0; k4 < 25; ++k4) {
            float4 h4 = *(const float4*)&h_s[k4 * 4];
            a0 += dot4_(*(const float4*)&wt[(k4 * G3 + l) * 4], h4);
            a1 += dot4_(*(const float4*)&wt[(k4 * G3 + 64 + l) * 4], h4);
            a2 += dot4_(*(const float4*)&wt[(k4 * G3 + 128 + l) * 4], h4);
            a3 += dot4_(*(const float4*)&wt[(k4 * G3 + 192 + l) * 4], h4);
            a4 += dot4_(*(const float4*)&wt[(k4 * G3 + row4) * 4], h4);
        }
        gh_s[l] = a0; gh_s[64 + l] = a1; gh_s[128 + l] = a2; gh_s[192 + l] = a3;
        if (l < 44) gh_s[256 + l] = a4;
        __syncthreads();

        const float* tc = tc_s + prev * G3;
        {
            float r = sigmoidf_(ga0 + tc[l]       + gh_s[l]);
            float z = sigmoidf_(ga1 + tc[100 + l] + gh_s[100 + l]);
            float n = tanhf_(   ga2 + tc[200 + l] + r * gh_s[200 + l]);
            float hn = (1.f - z) * n + z * hc0;
            hc0 = hn; h_s[l] = hn;
        }
        if (l < 36) {
            float r = sigmoidf_(gb0 + tc[64 + l]  + gh_s[64 + l]);
            float z = sigmoidf_(gb1 + tc[164 + l] + gh_s[164 + l]);
            float n = tanhf_(   gb2 + tc[264 + l] + r * gh_s[264 + l]);
            float hn = (1.f - z) * n + z * hc1;
            hc1 = hn; h_s[64 + l] = hn;
        }
        __syncthreads();

        // logits: 40 lanes, 4 partials per class
        if (l < 40) {
            int c = l >> 2, part = l & 3;
            float acc = 0.f;
            for (int k = part; k < H_; k += 4) acc += hl_s[c * H_ + k] * h_s[k];
            acc += __shfl_xor(acc, 1);
            acc += __shfl_xor(acc, 2);
            if (part == 0) lg_s[c] = acc + hlb_r;
        }
        __syncthreads();

        // softmax + argmax over 16-lane group
        float v = (l < NC_) ? lg_s[l] : -INFINITY;
        float mx = v; int am = l;
#pragma unroll
        for (int m = 8; m; m >>= 1) {
            float ov = __shfl_xor(mx, m);
            int   oa = __shfl_xor(am, m);
            if (ov > mx || (ov == mx && oa < am)) { mx = ov; am = oa; }
        }
        float e = (l < NC_) ? __expf(v - mx) : 0.f;
        float se = e;
#pragma unroll
        for (int m = 8; m; m >>= 1) se += __shfl_xor(se, m);
        float lse = mx + __logf(se);
        if (l < NC_) out[((size_t)t * B_ + b) * NC_ + l] = v - lse;
        prev = __shfl(am, 0);
    }
}

// ---------------------------------------------------------------------------
extern "C" void kernel_launch(void* const* d_in, const int* in_sizes, int n_in,
                              void* d_out, int out_size, void* d_ws, size_t ws_size,
                              hipStream_t stream)
{
    const float* hs   = (const float*)d_in[0];
    const int*   cb   = (const int*)  d_in[1];
    const float* fc5w = (const float*)d_in[2];
    const float* fc5b = (const float*)d_in[3];
    const float* ewif = (const float*)d_in[4];
    const float* ewhf = (const float*)d_in[5];
    const float* ebif = (const float*)d_in[6];
    const float* ebhf = (const float*)d_in[7];
    const float* ewib = (const float*)d_in[8];
    const float* ewhb = (const float*)d_in[9];
    const float* ebib = (const float*)d_in[10];
    const float* ebhb = (const float*)d_in[11];
    const float* emb  = (const float*)d_in[12];
    const float* l1w  = (const float*)d_in[13];
    const float* l1b  = (const float*)d_in[14];
    const float* dwih = (const float*)d_in[15];
    const float* dwhh = (const float*)d_in[16];
    const float* dbih = (const float*)d_in[17];
    const float* dbhh = (const float*)d_in[18];
    const float* h2lw = (const float*)d_in[19];
    const float* h2lb = (const float*)d_in[20];
    float* out = (float*)d_out;

    float* ws   = (float*)d_ws;
    float* doc  = ws;                  // [32*64, 768]   = 1572864
    float* gi   = doc  + 1572864;      // [2048, 600]    = 1228800
    float* out1 = gi   + 1228800;      // [2048, 200]    = 409600
    float* hT   = out1 + 409600;       // [64, 100]      = 6400
    float* W2   = hT   + 6400;         // [300, 200]     = 60000
    float* b2   = W2   + 60000;        // [300]
    float* tcg  = b2   + 320;          // [10, 300]      = 3000
    float* gil  = tcg  + 3072;         // [2048, 300]    = 614400

    pool_kernel<<<dim3(S_, B_), 256, 0, stream>>>(hs, cb, fc5w, fc5b, doc);
    w2_precompute<<<G3, 256, 0, stream>>>(dwih, l1w, l1b, emb, dbih, W2, b2, tcg);
    gemm_enc<<<dim3(10, 32), 256, 0, stream>>>(doc, ewif, ewib, ebif, ebib, gi);
    enc_scan<<<128, 64, 0, stream>>>(gi, ewhf, ewhb, ebhf, ebhb, out1, hT);
    {   // gil = out1 @ W2.T + b2   [2048,200]x[300,200] -> [2048,300]
        size_t sh = (size_t)(64 + 8) * 201 * sizeof(float);
        small_gemm<<<dim3(5, 256), 256, sh, stream>>>(out1, 200, 200,
                                                      W2, 200, 0, b2,
                                                      gil, 300, 300, 8, 64);
    }
    dec_scan<<<64, 64, 0, stream>>>(gil, dwhh, dbhh, tcg,
                                    h2lw, h2lb, hT, out);
}

// Round 6
// 301.291 us; speedup vs baseline: 1.5777x; 1.5777x over previous
//
#include <hip/hip_runtime.h>
#include <hip/hip_bf16.h>
#include <math.h>

#define B_ 64
#define L_ 512
#define D_ 768
#define J_ 31
#define S_ 32
#define H_ 100
#define G3 300
#define NC_ 10
#define EMB_ 50

__device__ __forceinline__ float sigmoidf_(float x) { return 1.0f / (1.0f + __expf(-x)); }
__device__ __forceinline__ float tanhf_(float x) {
    float e = __expf(2.0f * x);
    return 1.0f - 2.0f / (e + 1.0f);
}
__device__ __forceinline__ float dot4_(float4 a, float4 b) {
    return a.x * b.x + a.y * b.y + a.z * b.z + a.w * b.w;
}

// ---------------------------------------------------------------------------
// K1: per-clause softmax-weighted pooling.  One block per (s, b).
// ---------------------------------------------------------------------------
#define TCAP 18
__global__ __launch_bounds__(256) void pool_kernel(
    const float* __restrict__ hs, const int* __restrict__ cb,
    const float* __restrict__ fc5w, const float* __restrict__ fc5b,
    float* __restrict__ doc)
{
    __shared__ __align__(16) float tile[TCAP * D_];
    __shared__ float sc_s[L_];
    __shared__ float red[8];

    int s = blockIdx.x, b = blockIdx.y;
    int start = (s == 0) ? 0 : cb[b * J_ + s - 1];
    int end   = (s == J_) ? L_ : cb[b * J_ + s];
    int nt = end - start;
    int tid = threadIdx.x;

    if (nt <= 0) {
        for (int d = tid; d < D_; d += 256) doc[((size_t)s * B_ + b) * D_ + d] = 0.f;
        return;
    }
    bool staged = (nt <= TCAP);
    const float* base = hs + ((size_t)b * L_ + start) * D_;

    if (staged) {
        const float4* b4 = (const float4*)base;
        float4* t4 = (float4*)tile;
        int n4 = nt * (D_ / 4);
        for (int i = tid; i < n4; i += 256) t4[i] = b4[i];
    }
    int lane = tid & 63, wv = tid >> 6;
    float fw[12];
#pragma unroll
    for (int i = 0; i < 12; ++i) fw[i] = fc5w[i * 64 + lane];
    __syncthreads();

    for (int t = wv; t < nt; t += 4) {
        const float* row = staged ? &tile[t * D_] : (base + (size_t)t * D_);
        float p = 0.f;
#pragma unroll
        for (int i = 0; i < 12; ++i) p += row[i * 64 + lane] * fw[i];
        for (int off = 32; off; off >>= 1) p += __shfl_xor(p, off);
        if (lane == 0) sc_s[t] = p + fc5b[0];
    }
    __syncthreads();

    float lm = -INFINITY;
    for (int i = tid; i < nt; i += 256) lm = fmaxf(lm, sc_s[i]);
    for (int off = 32; off; off >>= 1) lm = fmaxf(lm, __shfl_xor(lm, off));
    if (lane == 0) red[wv] = lm;
    __syncthreads();
    float mx = fmaxf(fmaxf(red[0], red[1]), fmaxf(red[2], red[3]));
    float ls = 0.f;
    for (int i = tid; i < nt; i += 256) {
        float e = __expf(sc_s[i] - mx);
        sc_s[i] = e;
        ls += e;
    }
    for (int off = 32; off; off >>= 1) ls += __shfl_xor(ls, off);
    if (lane == 0) red[4 + wv] = ls;
    __syncthreads();
    float inv = 1.f / (red[4] + red[5] + red[6] + red[7]);

    float acc0 = 0.f, acc1 = 0.f, acc2 = 0.f;
    for (int t = 0; t < nt; ++t) {
        float w = sc_s[t] * inv;
        const float* row = staged ? &tile[t * D_] : (base + (size_t)t * D_);
        acc0 += w * row[tid];
        acc1 += w * row[256 + tid];
        acc2 += w * row[512 + tid];
    }
    float* o = doc + ((size_t)s * B_ + b) * D_;
    o[tid] = acc0; o[256 + tid] = acc1; o[512 + tid] = acc2;
}

// ---------------------------------------------------------------------------
// K2: gi = doc @ [Wf;Wb].T + [bf;bb]   M=2048, N=600, K=768  (64x64 tiles)
// ---------------------------------------------------------------------------
__global__ __launch_bounds__(256) void gemm_enc(
    const float* __restrict__ A,
    const float* __restrict__ Wf, const float* __restrict__ Wb,
    const float* __restrict__ bf_, const float* __restrict__ bb_,
    float* __restrict__ C)
{
    __shared__ __align__(16) float As[16][68];
    __shared__ __align__(16) float Ws[16][68];
    int n0 = blockIdx.x * 64, m0 = blockIdx.y * 64;
    int tid = threadIdx.x;
    int tx = tid & 15, ty = tid >> 4;
    int lr = tid >> 2, lk4 = tid & 3;
    float acc[4][4] = {};

    for (int kk = 0; kk < D_; kk += 16) {
        float4 av = *(const float4*)(A + ((size_t)(m0 + lr)) * D_ + kk + lk4 * 4);
        As[lk4 * 4 + 0][lr] = av.x; As[lk4 * 4 + 1][lr] = av.y;
        As[lk4 * 4 + 2][lr] = av.z; As[lk4 * 4 + 3][lr] = av.w;
        int n = n0 + lr;
        float4 wvv = make_float4(0.f, 0.f, 0.f, 0.f);
        if (n < G3)      wvv = *(const float4*)(Wf + (size_t)n * D_ + kk + lk4 * 4);
        else if (n < 600) wvv = *(const float4*)(Wb + (size_t)(n - G3) * D_ + kk + lk4 * 4);
        Ws[lk4 * 4 + 0][lr] = wvv.x; Ws[lk4 * 4 + 1][lr] = wvv.y;
        Ws[lk4 * 4 + 2][lr] = wvv.z; Ws[lk4 * 4 + 3][lr] = wvv.w;
        __syncthreads();
#pragma unroll
        for (int k = 0; k < 16; ++k) {
            float4 a4 = *(const float4*)&As[k][ty * 4];
            float4 w4 = *(const float4*)&Ws[k][tx * 4];
            float ai[4] = {a4.x, a4.y, a4.z, a4.w};
            float wj[4] = {w4.x, w4.y, w4.z, w4.w};
#pragma unroll
            for (int i = 0; i < 4; ++i)
#pragma unroll
                for (int j = 0; j < 4; ++j) acc[i][j] += ai[i] * wj[j];
        }
        __syncthreads();
    }
#pragma unroll
    for (int j = 0; j < 4; ++j) {
        int n = n0 + tx * 4 + j;
        if (n >= 600) continue;
        float bias = (n < G3) ? bf_[n] : bb_[n - G3];
#pragma unroll
        for (int i = 0; i < 4; ++i) {
            int m = m0 + ty * 4 + i;
            C[(size_t)m * 600 + n] = acc[i][j] + bias;
        }
    }
}

// ---------------------------------------------------------------------------
// K3: encoder scans. 128 blocks (64 batch x 2 dir), 320 threads (5 waves).
// Whh transposed in LDS (conflict-free chunked rows); per-step: 2 barriers.
// ---------------------------------------------------------------------------
#define WT_N (25 * G3 * 4)   // 30000 floats = 120000 B
__global__ __launch_bounds__(320) void enc_scan(
    const float* __restrict__ gi,
    const float* __restrict__ whh_f, const float* __restrict__ whh_b,
    const float* __restrict__ bhh_f, const float* __restrict__ bhh_b,
    float* __restrict__ out1, float* __restrict__ hT)
{
    __shared__ __align__(16) float wt[WT_N];
    __shared__ __align__(16) float h_s[H_];
    __shared__ float gh_s[G3];

    int bid = blockIdx.x;
    int b = bid & 63;
    bool bwd = (bid >= 64);
    const float* whh = bwd ? whh_b : whh_f;
    const float* bhh = bwd ? bhh_b : bhh_f;
    int tid = threadIdx.x;

    for (int i4 = tid; i4 < 7500; i4 += 320) {
        int j = i4 / 25, k4 = i4 - j * 25;
        float4 v = *(const float4*)(whh + (size_t)j * H_ + k4 * 4);
        *(float4*)&wt[(k4 * G3 + j) * 4] = v;
    }
    float bh = (tid < G3) ? bhh[tid] : 0.f;
    float hc = 0.f;
    if (tid < H_) h_s[tid] = 0.f;
    __syncthreads();

    const int goff = bwd ? G3 : 0;
    const int ooff = bwd ? H_ : 0;

    for (int step = 0; step < S_; ++step) {
        int t = bwd ? (S_ - 1 - step) : step;
        // phase A: issue g loads (gate threads) + matvec
        float ga0 = 0.f, ga1 = 0.f, ga2 = 0.f;
        if (tid < H_) {
            const float* g = gi + ((size_t)t * B_ + b) * 600 + goff;
            ga0 = g[tid]; ga1 = g[H_ + tid]; ga2 = g[2 * H_ + tid];
        }
        if (tid < G3) {
            float acc = bh;
#pragma unroll
            for (int k4 = 0; k4 < 25; ++k4) {
                float4 w4 = *(const float4*)&wt[(k4 * G3 + tid) * 4];
                float4 h4 = *(const float4*)&h_s[k4 * 4];
                acc += dot4_(w4, h4);
            }
            gh_s[tid] = acc;
        }
        __syncthreads();
        // phase B: gates
        if (tid < H_) {
            float r = sigmoidf_(ga0 + gh_s[tid]);
            float z = sigmoidf_(ga1 + gh_s[H_ + tid]);
            float n = tanhf_(ga2 + r * gh_s[2 * H_ + tid]);
            float hn = (1.f - z) * n + z * hc;
            hc = hn; h_s[tid] = hn;
            out1[((size_t)t * B_ + b) * 200 + ooff + tid] = hn;
        }
        __syncthreads();
    }
    if (!bwd && tid < H_) hT[b * H_ + tid] = hc;
}

// ---------------------------------------------------------------------------
// K4a: W2[n] = dwih[n][50:150] @ l1w ; b2[n] ; tcg[c][n] = bih[n]+emb[c].dwih[n][0:50]
// ---------------------------------------------------------------------------
__global__ __launch_bounds__(256) void w2_precompute(
    const float* __restrict__ dwih, const float* __restrict__ l1w,
    const float* __restrict__ l1b, const float* __restrict__ emb,
    const float* __restrict__ bih,
    float* __restrict__ W2, float* __restrict__ b2, float* __restrict__ tcg)
{
    __shared__ float dw_s[H_];
    int n = blockIdx.x;
    int k = threadIdx.x;
    if (k < H_) dw_s[k] = dwih[(size_t)n * 150 + 50 + k];
    __syncthreads();
    if (k < 200) {
        float acc = 0.f;
        for (int i = 0; i < H_; ++i) acc += dw_s[i] * l1w[(size_t)i * 200 + k];
        W2[(size_t)n * 200 + k] = acc;
    } else if (k == 200) {
        float acc = 0.f;
        for (int i = 0; i < H_; ++i) acc += dw_s[i] * l1b[i];
        b2[n] = acc;
    } else if (k < 211) {
        int c = k - 201;
        float acc = bih[n];
        const float* er = emb + c * EMB_;
        const float* wr = dwih + (size_t)n * 150;
        for (int e = 0; e < EMB_; ++e) acc += er[e] * wr[e];
        tcg[c * G3 + n] = acc;
    }
}

// ---------------------------------------------------------------------------
// K4b: generic small NT GEMM
// ---------------------------------------------------------------------------
__global__ void small_gemm(
    const float* __restrict__ A, int lda, int K,
    const float* __restrict__ W, int wstride, int woff,
    const float* __restrict__ bias,
    float* __restrict__ C, int N, int ldc,
    int BM, int nChunk)
{
    extern __shared__ float sm[];
    int Kp = K + 1;
    float* Wl = sm;
    float* Al = sm + (size_t)nChunk * Kp;
    int nBase = blockIdx.x * nChunk;
    int nCnt = min(nChunk, N - nBase);
    int m0 = blockIdx.y * BM;

    for (int i = threadIdx.x; i < nCnt * K; i += blockDim.x) {
        int n = i / K, k = i - n * K;
        Wl[n * Kp + k] = W[(size_t)(nBase + n) * wstride + woff + k];
    }
    for (int i = threadIdx.x; i < BM * K; i += blockDim.x) {
        int mi = i / K, k = i - mi * K;
        Al[mi * Kp + k] = A[(size_t)(m0 + mi) * lda + k];
    }
    __syncthreads();

    for (int o = threadIdx.x; o < BM * nCnt; o += blockDim.x) {
        int mi = o / nCnt, n = o - mi * nCnt;
        const float* wr = &Wl[n * Kp];
        const float* ar = &Al[mi * Kp];
        float a0 = 0.f, a1 = 0.f, a2 = 0.f, a3 = 0.f;
        int k = 0;
        for (; k + 4 <= K; k += 4) {
            a0 += ar[k] * wr[k];
            a1 += ar[k + 1] * wr[k + 1];
            a2 += ar[k + 2] * wr[k + 2];
            a3 += ar[k + 3] * wr[k + 3];
        }
        for (; k < K; ++k) a0 += ar[k] * wr[k];
        float v = (a0 + a1) + (a2 + a3);
        if (bias) v += bias[nBase + n];
        C[(size_t)(m0 + mi) * ldc + nBase + n] = v;
    }
}

// ---------------------------------------------------------------------------
// K5: decoder scan. One block per batch element, 384 threads = 6 waves.
// Waves 0-4: matvec + gates.  Wave 5: logits/argmax/log-softmax of the
// PREVIOUS step, concurrent with the matvec (prev is only needed at gates).
// 2 barriers/step.  Loop runs S+1 iterations (last = final logits only).
// ---------------------------------------------------------------------------
__global__ __launch_bounds__(384) void dec_scan(
    const float* __restrict__ gi_lin,
    const float* __restrict__ whh, const float* __restrict__ bhh,
    const float* __restrict__ tcg,
    const float* __restrict__ h2lw, const float* __restrict__ h2lb,
    const float* __restrict__ hT, float* __restrict__ out)
{
    __shared__ __align__(16) float wt[WT_N];     // 120000 B
    __shared__ float tc_s[NC_ * G3];             // 12000 B
    __shared__ float hl_s[NC_ * H_];             // 4000 B
    __shared__ __align__(16) float h_s[H_];
    __shared__ float gh_s[G3];
    __shared__ int prev_s;

    int b = blockIdx.x;
    int tid = threadIdx.x;

    for (int i4 = tid; i4 < 7500; i4 += 384) {
        int j = i4 / 25, k4 = i4 - j * 25;
        float4 v = *(const float4*)(whh + (size_t)j * H_ + k4 * 4);
        *(float4*)&wt[(k4 * G3 + j) * 4] = v;
    }
    for (int idx = tid; idx < NC_ * G3; idx += 384) tc_s[idx] = tcg[idx];
    for (int idx = tid; idx < NC_ * H_; idx += 384) hl_s[idx] = h2lw[idx];

    float bh = (tid < G3) ? bhh[tid] : 0.f;
    float hc = (tid < H_) ? hT[b * H_ + tid] : 0.f;
    if (tid < H_) h_s[tid] = hc;
    if (tid == 0) prev_s = 0;
    int l5 = tid - 320;                          // wave-5 lane (0..63) if >=0
    float hlb_r = (l5 >= 0 && l5 < NC_) ? h2lb[l5] : 0.f;
    __syncthreads();

    for (int t = 0; t <= S_; ++t) {
        // ---------------- phase A ----------------
        float ga0 = 0.f, ga1 = 0.f, ga2 = 0.f;
        if (tid < 320) {
            if (t < S_) {
                if (tid < H_) {
                    const float* g = gi_lin + ((size_t)t * B_ + b) * G3;
                    ga0 = g[tid]; ga1 = g[H_ + tid]; ga2 = g[2 * H_ + tid];
                }
                if (tid < G3) {
                    float acc = bh;
#pragma unroll
                    for (int k4 = 0; k4 < 25; ++k4) {
                        float4 w4 = *(const float4*)&wt[(k4 * G3 + tid) * 4];
                        float4 h4 = *(const float4*)&h_s[k4 * 4];
                        acc += dot4_(w4, h4);
                    }
                    gh_s[tid] = acc;
                }
            }
        } else if (t >= 1) {
            // wave 5: logits for step t-1 from current h_s
            float acc = 0.f;
            if (l5 < 40) {
                int c = l5 >> 2, part = l5 & 3;
                const float* hr = hl_s + c * H_;
                for (int k = part; k < H_; k += 4) acc += hr[k] * h_s[k];
                acc += __shfl_xor(acc, 1);
                acc += __shfl_xor(acc, 2);
            }
            float src = __shfl(acc, (l5 < NC_) ? 4 * l5 : 0);
            float v = (l5 < NC_) ? src + hlb_r : -INFINITY;
            float mx = v; int am = (l5 < 16) ? l5 : 15;
#pragma unroll
            for (int m = 8; m; m >>= 1) {
                float ov = __shfl_xor(mx, m);
                int   oa = __shfl_xor(am, m);
                if (ov > mx || (ov == mx && oa < am)) { mx = ov; am = oa; }
            }
            float e = (l5 < NC_) ? __expf(v - mx) : 0.f;
            float se = e;
#pragma unroll
            for (int m = 8; m; m >>= 1) se += __shfl_xor(se, m);
            float lse = mx + __logf(se);
            if (l5 < NC_) out[((size_t)(t - 1) * B_ + b) * NC_ + l5] = v - lse;
            if (l5 == 0) prev_s = am;
        }
        __syncthreads();
        // ---------------- phase B ----------------
        if (t < S_ && tid < H_) {
            const float* tc = tc_s + prev_s * G3;
            float r = sigmoidf_(ga0 + tc[tid]          + gh_s[tid]);
            float z = sigmoidf_(ga1 + tc[H_ + tid]     + gh_s[H_ + tid]);
            float n = tanhf_(   ga2 + tc[2 * H_ + tid] + r * gh_s[2 * H_ + tid]);
            float hn = (1.f - z) * n + z * hc;
            hc = hn; h_s[tid] = hn;
        }
        __syncthreads();
    }
}

// ---------------------------------------------------------------------------
extern "C" void kernel_launch(void* const* d_in, const int* in_sizes, int n_in,
                              void* d_out, int out_size, void* d_ws, size_t ws_size,
                              hipStream_t stream)
{
    const float* hs   = (const float*)d_in[0];
    const int*   cb   = (const int*)  d_in[1];
    const float* fc5w = (const float*)d_in[2];
    const float* fc5b = (const float*)d_in[3];
    const float* ewif = (const float*)d_in[4];
    const float* ewhf = (const float*)d_in[5];
    const float* ebif = (const float*)d_in[6];
    const float* ebhf = (const float*)d_in[7];
    const float* ewib = (const float*)d_in[8];
    const float* ewhb = (const float*)d_in[9];
    const float* ebib = (const float*)d_in[10];
    const float* ebhb = (const float*)d_in[11];
    const float* emb  = (const float*)d_in[12];
    const float* l1w  = (const float*)d_in[13];
    const float* l1b  = (const float*)d_in[14];
    const float* dwih = (const float*)d_in[15];
    const float* dwhh = (const float*)d_in[16];
    const float* dbih = (const float*)d_in[17];
    const float* dbhh = (const float*)d_in[18];
    const float* h2lw = (const float*)d_in[19];
    const float* h2lb = (const float*)d_in[20];
    float* out = (float*)d_out;

    float* ws   = (float*)d_ws;
    float* doc  = ws;                  // [32*64, 768]   = 1572864
    float* gi   = doc  + 1572864;      // [2048, 600]    = 1228800
    float* out1 = gi   + 1228800;      // [2048, 200]    = 409600
    float* hT   = out1 + 409600;       // [64, 100]      = 6400
    float* W2   = hT   + 6400;         // [300, 200]     = 60000
    float* b2   = W2   + 60000;        // [300]
    float* tcg  = b2   + 320;          // [10, 300]      = 3000
    float* gil  = tcg  + 3072;         // [2048, 300]    = 614400

    pool_kernel<<<dim3(S_, B_), 256, 0, stream>>>(hs, cb, fc5w, fc5b, doc);
    w2_precompute<<<G3, 256, 0, stream>>>(dwih, l1w, l1b, emb, dbih, W2, b2, tcg);
    gemm_enc<<<dim3(10, 32), 256, 0, stream>>>(doc, ewif, ewib, ebif, ebib, gi);
    enc_scan<<<128, 320, 0, stream>>>(gi, ewhf, ewhb, ebhf, ebhb, out1, hT);
    {   // gil = out1 @ W2.T + b2   [2048,200]x[300,200] -> [2048,300]
        size_t sh = (size_t)(64 + 8) * 201 * sizeof(float);
        small_gemm<<<dim3(5, 256), 256, sh, stream>>>(out1, 200, 200,
                                                      W2, 200, 0, b2,
                                                      gil, 300, 300, 8, 64);
    }
    dec_scan<<<64, 384, 0, stream>>>(gil, dwhh, dbhh, tcg,
                                     h2lw, h2lb, hT, out);
}